// Round 4
// baseline (26.462 us; speedup 1.0000x reference)
//
#include <hip/hip_runtime.h>

// Cond_PlanarTrans: out = s + u * tanh(w*s + b)
//  w = relu(o*W1[n]+b1[n]), u = relu(o*W2[n]+b2[n]), b = relu(o*W3[n]+b3[n])
//  n = m[b,p]; N_M=8, O_DIM=1 -> pure elementwise over 8,388,608 floats.
// R3 evidence: FETCH=50MB (L3 absorbs reads), VALUBusy 8.6%, VGPR=32 ->
//   latency-bound; compiler re-serialized the 12-load cluster (32 VGPRs can't
//   hold 12 float4 payloads). Fixes: sched_barrier(0) to pin the load phase,
//   packed-weight LDS (b128+b64 per elem instead of 6x b32), no predication
//   on the exact-cover path.

typedef float f32x4 __attribute__((ext_vector_type(4)));
typedef float f32x2 __attribute__((ext_vector_type(2)));

__device__ __forceinline__ float fast_tanh(float x) {
    // tanh(x) = 1 - 2/(exp(2x)+1). Exact at saturation, no branches.
    float e = __builtin_amdgcn_exp2f(x * 2.88539008177793f);
    return fmaf(-2.0f, __builtin_amdgcn_rcpf(e + 1.0f), 1.0f);
}

#define CHUNKS 4

__device__ __forceinline__ void stage_weights(
    float (*wts)[8],
    const float* W1, const float* b1,
    const float* W2, const float* b2,
    const float* W3, const float* b3, int t)
{
    if (t < 8) {
        wts[t][0] = W1[t];
        wts[t][1] = b1[t];
        wts[t][2] = W2[t];
        wts[t][3] = b2[t];
        wts[t][4] = W3[t];
        wts[t][5] = b3[t];
    }
    __syncthreads();
}

__device__ __forceinline__ float planar_elem(const float (*wts)[8],
                                             int n, float oo, float ss)
{
    const f32x4 a  = *(const f32x4*)&wts[n][0];   // W1,b1,W2,b2 (ds_read_b128)
    const f32x2 c2 = *(const f32x2*)&wts[n][4];   // W3,b3       (ds_read_b64)
    float w  = fmaxf(fmaf(oo, a[0], a[1]), 0.0f);
    float u  = fmaxf(fmaf(oo, a[2], a[3]), 0.0f);
    float bb = fmaxf(fmaf(oo, c2[0], c2[1]), 0.0f);
    return fmaf(u, fast_tanh(fmaf(w, ss, bb)), ss);
}

// Fast path: grid*block*CHUNKS == n4 exactly (actual bench shape).
__global__ __launch_bounds__(256) void cond_planar_exact(
    const int4* __restrict__ m4,
    const float4* __restrict__ s4,
    const float4* __restrict__ o4,
    const float* __restrict__ W1, const float* __restrict__ b1,
    const float* __restrict__ W2, const float* __restrict__ b2,
    const float* __restrict__ W3, const float* __restrict__ b3,
    float4* __restrict__ out4,
    int stride)
{
    __shared__ float wts[8][8];   // [n] = {W1,b1,W2,b2,W3,b3,pad,pad}
    int t = threadIdx.x;
    stage_weights(wts, W1, b1, W2, b2, W3, b3, t);

    int i0 = blockIdx.x * blockDim.x + t;

    int4   mv[CHUNKS];
    float4 sv[CHUNKS];
    float4 ov[CHUNKS];

    // ---- load phase: 12 independent 16B loads, pinned before compute ----
#pragma unroll
    for (int c = 0; c < CHUNKS; ++c) {
        int i = i0 + c * stride;
        mv[c] = m4[i];
        sv[c] = s4[i];
        ov[c] = o4[i];
    }
    __builtin_amdgcn_sched_barrier(0);   // nothing crosses: loads stay clustered

    // ---- compute + store phase ----
#pragma unroll
    for (int c = 0; c < CHUNKS; ++c) {
        int   mi[4] = { mv[c].x, mv[c].y, mv[c].z, mv[c].w };
        float ss[4] = { sv[c].x, sv[c].y, sv[c].z, sv[c].w };
        float oo[4] = { ov[c].x, ov[c].y, ov[c].z, ov[c].w };
        float r[4];
#pragma unroll
        for (int j = 0; j < 4; ++j)
            r[j] = planar_elem(wts, mi[j] & 7, oo[j], ss[j]);
        out4[i0 + c * stride] = make_float4(r[0], r[1], r[2], r[3]);
    }
}

// Safe fallback (predicated) for non-exact shapes.
__global__ __launch_bounds__(256) void cond_planar_safe(
    const int4* __restrict__ m4,
    const float4* __restrict__ s4,
    const float4* __restrict__ o4,
    const float* __restrict__ W1, const float* __restrict__ b1,
    const float* __restrict__ W2, const float* __restrict__ b2,
    const float* __restrict__ W3, const float* __restrict__ b3,
    float4* __restrict__ out4,
    int n4, int stride)
{
    __shared__ float wts[8][8];
    int t = threadIdx.x;
    stage_weights(wts, W1, b1, W2, b2, W3, b3, t);

    for (int i = blockIdx.x * blockDim.x + t; i < n4; i += stride) {
        int4   mv = m4[i];
        float4 sv = s4[i];
        float4 ov = o4[i];
        int   mi[4] = { mv.x, mv.y, mv.z, mv.w };
        float ss[4] = { sv.x, sv.y, sv.z, sv.w };
        float oo[4] = { ov.x, ov.y, ov.z, ov.w };
        float r[4];
#pragma unroll
        for (int j = 0; j < 4; ++j)
            r[j] = planar_elem(wts, mi[j] & 7, oo[j], ss[j]);
        out4[i] = make_float4(r[0], r[1], r[2], r[3]);
    }
}

extern "C" void kernel_launch(void* const* d_in, const int* in_sizes, int n_in,
                              void* d_out, int out_size, void* d_ws, size_t ws_size,
                              hipStream_t stream)
{
    const int*   m  = (const int*)d_in[0];
    const float* s  = (const float*)d_in[1];
    const float* o  = (const float*)d_in[2];
    const float* W1 = (const float*)d_in[3];
    const float* b1 = (const float*)d_in[4];
    const float* W2 = (const float*)d_in[5];
    const float* b2 = (const float*)d_in[6];
    const float* W3 = (const float*)d_in[7];
    const float* b3 = (const float*)d_in[8];
    float* out = (float*)d_out;

    int n  = out_size;     // 8,388,608
    const int block = 256;

    if ((n & 3) == 0) {
        int n4 = n / 4;    // 2,097,152 float4 elements
        int grid = (n4 + CHUNKS * block - 1) / (CHUNKS * block);   // 2048
        int stride = grid * block;
        if (grid * block * CHUNKS == n4) {
            cond_planar_exact<<<grid, block, 0, stream>>>(
                (const int4*)m, (const float4*)s, (const float4*)o,
                W1, b1, W2, b2, W3, b3, (float4*)out, stride);
        } else {
            cond_planar_safe<<<grid, block, 0, stream>>>(
                (const int4*)m, (const float4*)s, (const float4*)o,
                W1, b1, W2, b2, W3, b3, (float4*)out, n4, stride);
        }
    }
}

// Round 5
// 24.669 us; speedup vs baseline: 1.0727x; 1.0727x over previous
//
#include <hip/hip_runtime.h>

// Cond_PlanarTrans: out = s + u * tanh(w*s + b)
//  w = relu(o*W1[n]+b1[n]), u = relu(o*W2[n]+b2[n]), b = relu(o*W3[n]+b3[n])
//  n = m[b,p]; N_M=8, O_DIM=1 -> pure elementwise over 8,388,608 floats.
// Evidence through R4: four per-thread-ILP structures all land 25.5-26.5 us;
//  FETCH=50MB / WRITE=33.5MB (L3 absorbs half the reads), bank conflicts 0,
//  VALUBusy 8.6% -> memory-system/overhead floor, not scheduling.
// R5: opposite pole - pure TLP. One float4 per thread, no loops, 8192 blocks,
//  minimal VGPRs, shortest dependency chain; latency hiding via wave count.

typedef float f32x4 __attribute__((ext_vector_type(4)));
typedef float f32x2 __attribute__((ext_vector_type(2)));

__device__ __forceinline__ float fast_tanh(float x) {
    // tanh(x) = 1 - 2/(exp(2x)+1). Exact at saturation, no branches.
    float e = __builtin_amdgcn_exp2f(x * 2.88539008177793f);
    return fmaf(-2.0f, __builtin_amdgcn_rcpf(e + 1.0f), 1.0f);
}

__device__ __forceinline__ void stage_weights(
    float (*wts)[8],
    const float* W1, const float* b1,
    const float* W2, const float* b2,
    const float* W3, const float* b3, int t)
{
    if (t < 8) {
        wts[t][0] = W1[t];
        wts[t][1] = b1[t];
        wts[t][2] = W2[t];
        wts[t][3] = b2[t];
        wts[t][4] = W3[t];
        wts[t][5] = b3[t];
    }
    __syncthreads();
}

__device__ __forceinline__ float planar_elem(const float (*wts)[8],
                                             int n, float oo, float ss)
{
    const f32x4 a  = *(const f32x4*)&wts[n][0];   // W1,b1,W2,b2 (ds_read_b128)
    const f32x2 c2 = *(const f32x2*)&wts[n][4];   // W3,b3       (ds_read_b64)
    float w  = fmaxf(fmaf(oo, a[0], a[1]), 0.0f);
    float u  = fmaxf(fmaf(oo, a[2], a[3]), 0.0f);
    float bb = fmaxf(fmaf(oo, c2[0], c2[1]), 0.0f);
    return fmaf(u, fast_tanh(fmaf(w, ss, bb)), ss);
}

// Pure-TLP kernel: one float4 per thread, no loop. Grid covers n4 exactly
// when n4 % 256 == 0 (bench shape: n4 = 2,097,152 -> 8192 blocks).
__global__ __launch_bounds__(256) void cond_planar_tlp(
    const int4* __restrict__ m4,
    const float4* __restrict__ s4,
    const float4* __restrict__ o4,
    const float* __restrict__ W1, const float* __restrict__ b1,
    const float* __restrict__ W2, const float* __restrict__ b2,
    const float* __restrict__ W3, const float* __restrict__ b3,
    float4* __restrict__ out4)
{
    __shared__ float wts[8][8];
    int t = threadIdx.x;
    stage_weights(wts, W1, b1, W2, b2, W3, b3, t);

    int i = blockIdx.x * blockDim.x + t;

    int4   mv = m4[i];
    float4 sv = s4[i];
    float4 ov = o4[i];

    int   mi[4] = { mv.x, mv.y, mv.z, mv.w };
    float ss[4] = { sv.x, sv.y, sv.z, sv.w };
    float oo[4] = { ov.x, ov.y, ov.z, ov.w };
    float r[4];
#pragma unroll
    for (int j = 0; j < 4; ++j)
        r[j] = planar_elem(wts, mi[j] & 7, oo[j], ss[j]);

    out4[i] = make_float4(r[0], r[1], r[2], r[3]);
}

// Predicated fallback for non-divisible shapes.
__global__ __launch_bounds__(256) void cond_planar_safe(
    const int4* __restrict__ m4,
    const float4* __restrict__ s4,
    const float4* __restrict__ o4,
    const float* __restrict__ W1, const float* __restrict__ b1,
    const float* __restrict__ W2, const float* __restrict__ b2,
    const float* __restrict__ W3, const float* __restrict__ b3,
    float4* __restrict__ out4,
    int n4, int stride)
{
    __shared__ float wts[8][8];
    int t = threadIdx.x;
    stage_weights(wts, W1, b1, W2, b2, W3, b3, t);

    for (int i = blockIdx.x * blockDim.x + t; i < n4; i += stride) {
        int4   mv = m4[i];
        float4 sv = s4[i];
        float4 ov = o4[i];
        int   mi[4] = { mv.x, mv.y, mv.z, mv.w };
        float ss[4] = { sv.x, sv.y, sv.z, sv.w };
        float oo[4] = { ov.x, ov.y, ov.z, ov.w };
        float r[4];
#pragma unroll
        for (int j = 0; j < 4; ++j)
            r[j] = planar_elem(wts, mi[j] & 7, oo[j], ss[j]);
        out4[i] = make_float4(r[0], r[1], r[2], r[3]);
    }
}

extern "C" void kernel_launch(void* const* d_in, const int* in_sizes, int n_in,
                              void* d_out, int out_size, void* d_ws, size_t ws_size,
                              hipStream_t stream)
{
    const int*   m  = (const int*)d_in[0];
    const float* s  = (const float*)d_in[1];
    const float* o  = (const float*)d_in[2];
    const float* W1 = (const float*)d_in[3];
    const float* b1 = (const float*)d_in[4];
    const float* W2 = (const float*)d_in[5];
    const float* b2 = (const float*)d_in[6];
    const float* W3 = (const float*)d_in[7];
    const float* b3 = (const float*)d_in[8];
    float* out = (float*)d_out;

    int n = out_size;      // 8,388,608
    const int block = 256;

    if ((n & 3) == 0 && ((n / 4) % block) == 0) {
        int n4   = n / 4;              // 2,097,152
        int grid = n4 / block;         // 8192 blocks, one float4/thread
        cond_planar_tlp<<<grid, block, 0, stream>>>(
            (const int4*)m, (const float4*)s, (const float4*)o,
            W1, b1, W2, b2, W3, b3, (float4*)out);
    } else {
        int n4 = (n + 3) / 4;
        int grid = (n4 + block - 1) / block;
        if (grid > 8192) grid = 8192;
        int stride = grid * block;
        cond_planar_safe<<<grid, block, 0, stream>>>(
            (const int4*)m, (const float4*)s, (const float4*)o,
            W1, b1, W2, b2, W3, b3, (float4*)out, n4, stride);
    }
}